// Round 5
// baseline (686.907 us; speedup 1.0000x reference)
//
#include <hip/hip_runtime.h>
#include <math.h>

// LRN on x[16,96,224,224] fp32.
// out = x * (2 + 1e-4 * boxfilter5x5(sum_c x^2))^(-0.75)
//
// Round 5: single persistent-grid fused kernel, software device-wide barrier.
//   phase A: s[b,h,w]  = sum_c x^2          (reads x 308 MB, writes s 3.2 MB)
//   phase S: sc = (2+1e-4*box5x5(s))^-0.75  (L2/L3-resident)
//   phase B: out = x * sc                   (re-reads x REVERSED for L3 hits,
//                                            NT stores for out -> no L3 pollution)
// Why: rounds 0-4 never showed my kernels in the profiled top-5 (all <190us,
// hidden under the harness ws-poison fill). One big kernel = visible counters,
// minus part/sum4 traffic, plus cross-phase L3 reuse of x (308MB vs 256MB L3).
// 512 blocks = 2 blocks/CU co-resident (launch_bounds-guaranteed), barrier via
// device-scope atomics + threadfence (guide 6 G16).

#define BB 16
#define CC 96
#define HH 224
#define WW 224
#define HW (HH * WW)          // 50176
#define CHW (CC * HW)         // 4816896
#define NPIX (BB * HW)        // 802816
#define W4 (WW / 4)           // 56
#define NCOL (BB * HH * W4)   // 200704 float4-columns
#define NCHUNK (NCOL / 256)   // 784 column-chunks of 256
#define S4 (HW / 4)           // float4 stride between channel planes
#define NBLK 512              // 2 blocks/CU on 256 CUs -- co-resident
#define NTHR 256
#define TTOT (NBLK * NTHR)    // 131072

typedef float v4f __attribute__((ext_vector_type(4)));

__device__ __forceinline__ void gbar(unsigned* cnt) {
    __syncthreads();
    if (threadIdx.x == 0) {
        __threadfence();                       // release: drain stores, wb L2
        atomicAdd(cnt, 1u);                    // device-scope
        while (__hip_atomic_load(cnt, __ATOMIC_RELAXED,
                                 __HIP_MEMORY_SCOPE_AGENT) < (unsigned)NBLK)
            __builtin_amdgcn_s_sleep(8);
        __threadfence();                       // acquire: inv L1/L2
    }
    __syncthreads();
}

__global__ void lrn_init(unsigned* bar) { bar[0] = 0u; bar[1] = 0u; }

__global__ __launch_bounds__(NTHR, 2) void lrn_fused(
        const float* __restrict__ x, float* __restrict__ out,
        float* __restrict__ s, float* __restrict__ sc, unsigned* bar) {
    const int tid = threadIdx.x;

    // ---------- phase A: s = sum_c x^2 ----------
    for (int k = blockIdx.x; k < NCHUNK; k += NBLK) {
        int t  = k * NTHR + tid;      // column id
        int w4 = t % W4;
        int bh = t / W4;              // b*HH + h
        int b  = bh / HH;
        int h  = bh % HH;
        size_t base = (((size_t)b * CHW + (size_t)h * WW) >> 2) + w4;
        const v4f* xp = (const v4f*)x + base;
        v4f acc = (v4f)(0.f);
        for (int c0 = 0; c0 < CC; c0 += 8) {
            v4f v[8];
#pragma unroll
            for (int u = 0; u < 8; ++u) v[u] = xp[(size_t)(c0 + u) * S4];
#pragma unroll
            for (int u = 0; u < 8; ++u) acc += v[u] * v[u];
        }
        ((v4f*)s)[t] = acc;
    }

    gbar(&bar[0]);

    // ---------- phase S: sc = (2 + 1e-4*box5x5(s))^-0.75 ----------
    for (int t = blockIdx.x * NTHR + tid; t < NPIX; t += TTOT) {
        int w  = t % WW;
        int bh = t / WW;
        int h  = bh % HH;
        float y = 0.f;
#pragma unroll
        for (int dh = -2; dh <= 2; ++dh) {
            int hh = h + dh;
            if (hh < 0 || hh >= HH) continue;          // zero pad (SAME); same b
            const float* row = s + (size_t)(bh + dh) * WW;
#pragma unroll
            for (int dw = -2; dw <= 2; ++dw) {
                int ww = w + dw;
                if (ww >= 0 && ww < WW) y += row[ww];
            }
        }
        sc[t] = powf(2.0f + 1e-4f * y, -0.75f);
    }

    gbar(&bar[1]);

    // ---------- phase B: out = x * sc (reversed chunk order for L3 reuse) ----
    for (int k = blockIdx.x; k < NCHUNK; k += NBLK) {
        int rk = NCHUNK - 1 - k;      // reverse: start where phase A ended
        int t  = rk * NTHR + tid;
        int w4 = t % W4;
        int bh = t / W4;
        int b  = bh / HH;
        int h  = bh % HH;
        size_t base = (((size_t)b * CHW + (size_t)h * WW) >> 2) + w4;
        v4f scv = ((const v4f*)sc)[t];
        const v4f* xp = (const v4f*)x + base;
        v4f* op = (v4f*)out + base;
        for (int c0 = 0; c0 < CC; c0 += 8) {
            v4f v[8];
#pragma unroll
            for (int u = 0; u < 8; ++u) v[u] = xp[(size_t)(c0 + u) * S4];
#pragma unroll
            for (int u = 0; u < 8; ++u)
                __builtin_nontemporal_store(v[u] * scv, &op[(size_t)(c0 + u) * S4]);
        }
    }
}

extern "C" void kernel_launch(void* const* d_in, const int* in_sizes, int n_in,
                              void* d_out, int out_size, void* d_ws, size_t ws_size,
                              hipStream_t stream) {
    const float* x = (const float*)d_in[0];
    float* out = (float*)d_out;
    float* s   = (float*)d_ws;                 // NPIX floats = 3.2 MB
    float* sc  = s + NPIX;                     // NPIX floats = 3.2 MB
    unsigned* bar = (unsigned*)(sc + NPIX);    // 2 uints (ws >= 6.5 MB)

    lrn_init<<<1, 1, 0, stream>>>(bar);
    lrn_fused<<<NBLK, NTHR, 0, stream>>>(x, out, s, sc, bar);
}